// Round 1
// baseline (880.419 us; speedup 1.0000x reference)
//
#include <hip/hip_runtime.h>

typedef _Float16 half8 __attribute__((ext_vector_type(8)));
typedef float floatx4 __attribute__((ext_vector_type(4)));

#define GLDS16(gsrc, ldst)                                                                  \
  __builtin_amdgcn_global_load_lds((const __attribute__((address_space(1))) void*)(gsrc),   \
                                   (__attribute__((address_space(3))) void*)(ldst), 16, 0, 0)

// ------------------------------------------------------------------
// fp32 -> fp16 convert, 8 elems/thread
// ------------------------------------------------------------------
__global__ __launch_bounds__(256) void cvt_f32_f16(const float* __restrict__ src,
                                                   _Float16* __restrict__ dst, int n8) {
  int i = blockIdx.x * 256 + threadIdx.x;
  if (i >= n8) return;
  const float4* s4 = (const float4*)src;
  float4 a = s4[2 * (size_t)i];
  float4 b = s4[2 * (size_t)i + 1];
  half8 h;
  h[0] = (_Float16)a.x; h[1] = (_Float16)a.y; h[2] = (_Float16)a.z; h[3] = (_Float16)a.w;
  h[4] = (_Float16)b.x; h[5] = (_Float16)b.y; h[6] = (_Float16)b.z; h[7] = (_Float16)b.w;
  *(half8*)(dst + 8 * (size_t)i) = h;
}

// ------------------------------------------------------------------
// NT GEMM: C[M,N] = A[M,K] @ W[N,K]^T + bias.
// 128x128 tile, BK=32, 4 waves (each 64x64), mfma_f32_16x16x32_f16.
// LDS staged via global_load_lds(16B) with XOR-swizzled source (slot ^ ((row>>1)&3))
// mode 0: C fp32 out.
// mode 1: fused qkv epilogue: bias + RoPE(first 32 dims of q,k) -> qf/kf/vf f16 [H][T][D].
// ------------------------------------------------------------------
__global__ __launch_bounds__(256) void gemm_nt(
    const _Float16* __restrict__ A, const _Float16* __restrict__ W,
    const float* __restrict__ bias, float* __restrict__ C,
    int M, int N, int K, int mode,
    _Float16* __restrict__ qfp, _Float16* __restrict__ kfp, _Float16* __restrict__ vfp) {
  __shared__ __align__(16) _Float16 As[128 * 32];
  __shared__ __align__(16) _Float16 Bs[128 * 32];
  const int tid = threadIdx.x;
  const int wave = tid >> 6, lane = tid & 63;
  const int wr = wave >> 1, wc = wave & 1;
  const int g = lane >> 4, r16 = lane & 15;
  const int m0 = blockIdx.y * 128, n0 = blockIdx.x * 128;

  // staging: 8 chunks of 1KB (16 rows x 64B); wave stages chunks {2w, 2w+1}
  const int c0 = wave * 2;
  const int srow0 = c0 * 16 + (lane >> 2);
  const int srow1 = srow0 + 16;
  const int sl = lane & 3;
  const _Float16* pa0 = A + (size_t)(m0 + srow0) * K + ((sl ^ ((srow0 >> 1) & 3)) << 3);
  const _Float16* pa1 = A + (size_t)(m0 + srow1) * K + ((sl ^ ((srow1 >> 1) & 3)) << 3);
  const _Float16* pw0 = W + (size_t)(n0 + srow0) * K + ((sl ^ ((srow0 >> 1) & 3)) << 3);
  const _Float16* pw1 = W + (size_t)(n0 + srow1) * K + ((sl ^ ((srow1 >> 1) & 3)) << 3);
  _Float16* da0 = As + c0 * 512;
  _Float16* da1 = As + c0 * 512 + 512;
  _Float16* db0 = Bs + c0 * 512;
  _Float16* db1 = Bs + c0 * 512 + 512;

  floatx4 acc[4][4] = {};

  for (int k0 = 0; k0 < K; k0 += 32) {
    __syncthreads();  // previous iter's ds_reads done
    GLDS16(pa0 + k0, da0);
    GLDS16(pa1 + k0, da1);
    GLDS16(pw0 + k0, db0);
    GLDS16(pw1 + k0, db1);
    __syncthreads();  // vmcnt(0) drained by compiler before barrier
    half8 af[4], bf[4];
#pragma unroll
    for (int m = 0; m < 4; ++m) {
      int row = wr * 64 + m * 16 + r16;
      af[m] = *(const half8*)(As + row * 32 + ((g ^ ((row >> 1) & 3)) << 3));
    }
#pragma unroll
    for (int n = 0; n < 4; ++n) {
      int row = wc * 64 + n * 16 + r16;
      bf[n] = *(const half8*)(Bs + row * 32 + ((g ^ ((row >> 1) & 3)) << 3));
    }
#pragma unroll
    for (int m = 0; m < 4; ++m)
#pragma unroll
      for (int n = 0; n < 4; ++n)
        acc[m][n] = __builtin_amdgcn_mfma_f32_16x16x32_f16(af[m], bf[n], acc[m][n], 0, 0, 0);
  }

  // epilogue: C layout row=(lane>>4)*4+ri, col=lane&15 (m89-verified)
  if (mode == 0) {
#pragma unroll
    for (int m = 0; m < 4; ++m)
#pragma unroll
      for (int ri = 0; ri < 4; ++ri) {
        int row = m0 + wr * 64 + m * 16 + g * 4 + ri;
#pragma unroll
        for (int n = 0; n < 4; ++n) {
          int col = n0 + wc * 64 + n * 16 + r16;
          C[(size_t)row * N + col] = acc[m][n][ri] + bias[col];
        }
      }
  } else {
    // block covers one (h, s): 128 cols inside a 384-col group
    const int bx = blockIdx.x;
    const int h = bx / 3, s = bx % 3;
    _Float16* dst = (s == 0) ? qfp : (s == 1 ? kfp : vfp);
    // theta_i = 10000^(-i/16) = 2^(-i*log2(10000)/16)
    const float theta = exp2f(-(float)r16 * 0.83048202372184058f);
#pragma unroll
    for (int m = 0; m < 4; ++m)
#pragma unroll
      for (int ri = 0; ri < 4; ++ri) {
        int t = m0 + wr * 64 + m * 16 + g * 4 + ri;
        float v[4];
#pragma unroll
        for (int n = 0; n < 4; ++n)
          v[n] = acc[m][n][ri] + bias[n0 + wc * 64 + n * 16 + r16];
        if (s < 2 && wc == 0) {
          // d = n*16 + r16 : n=0 -> d<16 (x1), n=1 -> 16<=d<32 (x2), same angle i=r16
          float sn, cs;
          sincosf((float)t * theta, &sn, &cs);
          float a0 = v[0], a1 = v[1];
          v[0] = a0 * cs - a1 * sn;
          v[1] = a1 * cs + a0 * sn;
        }
        size_t rb = ((size_t)h * 2048 + t) * 128 + wc * 64 + r16;
#pragma unroll
        for (int n = 0; n < 4; ++n) dst[rb + n * 16] = (_Float16)v[n];
      }
  }
}

// ------------------------------------------------------------------
// Flash attention, causal. 512 blocks: (h, qt) with long-tiles-first pairing.
// 4 waves x 32 q-rows, KVBLK=32. K via swizzled global_load_lds; V reg-staged
// transposed into LDS; P transposed through padded LDS; online softmax.
// ------------------------------------------------------------------
__global__ __launch_bounds__(256) void attn(const _Float16* __restrict__ qf,
                                            const _Float16* __restrict__ kf,
                                            const _Float16* __restrict__ vf,
                                            _Float16* __restrict__ yf) {
  __shared__ __align__(16) _Float16 Kl[32 * 128];
  __shared__ __align__(16) _Float16 Vt[128 * 32];  // V^T tile: [d][key]
  __shared__ __align__(16) _Float16 Pl[4][32 * 40];

  const int bid = blockIdx.x;
  const int halfsel = bid >> 8, idx = bid & 255;
  const int h = idx & 31, qb = idx >> 5;
  const int qt = halfsel ? qb : 15 - qb;  // pair qt with 15-qt across dispatch halves
  const int tid = threadIdx.x, wave = tid >> 6, lane = tid & 63;
  const int g = lane >> 4, r16 = lane & 15;
  const size_t hT = (size_t)h * 2048;

  const int q0 = qt * 128 + wave * 32;
  half8 qfrag[2][4];
#pragma unroll
  for (int i = 0; i < 2; ++i)
#pragma unroll
    for (int kk = 0; kk < 4; ++kk)
      qfrag[i][kk] = *(const half8*)(qf + (hT + q0 + i * 16 + r16) * 128 + kk * 32 + g * 8);

  floatx4 O[2][8] = {};
  float mrow[2][4], lrow[2][4];
#pragma unroll
  for (int i = 0; i < 2; ++i)
#pragma unroll
    for (int ri = 0; ri < 4; ++ri) {
      mrow[i][ri] = -3.0e38f;
      lrow[i][ri] = 0.0f;
    }

  const int vkey = tid >> 3;         // 0..31
  const int d0 = (tid & 7) << 4;     // 0..112
  const int nkt = (qt + 1) * 4;
  const float scale = 0.08838834764831845f;  // 1/sqrt(128)

  for (int kt = 0; kt < nkt; ++kt) {
    const int k0 = kt * 32;
    __syncthreads();
    // --- stage K (8 chunks of 1KB, swizzled source, linear LDS dest) ---
#pragma unroll
    for (int c = 0; c < 2; ++c) {
      int ch = wave * 2 + c;
      int krow = ch * 4 + (lane >> 4);
      const _Float16* src = kf + (hT + k0 + krow) * 128 + (((lane & 15) ^ (krow & 7)) << 3);
      GLDS16(src, ((_Float16*)Kl) + ch * 512);
    }
    // --- stage V transposed: Vt[d][key], slot-swizzled ---
    {
      const _Float16* vsrc = vf + (hT + k0 + vkey) * 128 + d0;
      half8 v0 = *(const half8*)vsrc;
      half8 v1 = *(const half8*)(vsrc + 8);
#pragma unroll
      for (int j = 0; j < 16; ++j) {
        int d = d0 + j;
        _Float16 val = (j < 8) ? v0[j] : v1[j - 8];
        int slot = (vkey >> 3) ^ ((d >> 1) & 3);
        Vt[d * 32 + slot * 8 + (vkey & 7)] = val;
      }
    }
    __syncthreads();

    // --- S = Q K^T (fp32 accum) ---
    floatx4 S[2][2] = {};
#pragma unroll
    for (int kk = 0; kk < 4; ++kk) {
      half8 kfr[2];
#pragma unroll
      for (int j = 0; j < 2; ++j) {
        int key = j * 16 + r16;
        kfr[j] = *(const half8*)(Kl + key * 128 + (((kk * 4 + g) ^ (key & 7)) << 3));
      }
#pragma unroll
      for (int i = 0; i < 2; ++i)
#pragma unroll
        for (int j = 0; j < 2; ++j)
          S[i][j] = __builtin_amdgcn_mfma_f32_16x16x32_f16(qfrag[i][kk], kfr[j], S[i][j], 0, 0, 0);
    }

    // --- online softmax (wave-parallel, shfl_xor over the 16-lane row group) ---
#pragma unroll
    for (int i = 0; i < 2; ++i) {
#pragma unroll
      for (int ri = 0; ri < 4; ++ri) {
        int qrow = q0 + i * 16 + g * 4 + ri;
        float s0 = S[i][0][ri] * scale;
        float s1 = S[i][1][ri] * scale;
        if (k0 + r16 > qrow) s0 = -1.0e30f;
        if (k0 + 16 + r16 > qrow) s1 = -1.0e30f;
        float rm = fmaxf(s0, s1);
        rm = fmaxf(rm, __shfl_xor(rm, 1));
        rm = fmaxf(rm, __shfl_xor(rm, 2));
        rm = fmaxf(rm, __shfl_xor(rm, 4));
        rm = fmaxf(rm, __shfl_xor(rm, 8));
        float mnew = fmaxf(mrow[i][ri], rm);
        float corr = __expf(mrow[i][ri] - mnew);
        mrow[i][ri] = mnew;
        float p0 = __expf(s0 - mnew);
        float p1 = __expf(s1 - mnew);
        float ps = p0 + p1;
        ps += __shfl_xor(ps, 1);
        ps += __shfl_xor(ps, 2);
        ps += __shfl_xor(ps, 4);
        ps += __shfl_xor(ps, 8);
        lrow[i][ri] = lrow[i][ri] * corr + ps;
#pragma unroll
        for (int n = 0; n < 8; ++n) O[i][n][ri] *= corr;
        int ql = i * 16 + g * 4 + ri;
        Pl[wave][ql * 40 + r16] = (_Float16)p0;
        Pl[wave][ql * 40 + 16 + r16] = (_Float16)p1;
      }
    }

    // --- O += P V ---
    {
      half8 pa0 = *(const half8*)(&Pl[wave][(r16)*40 + g * 8]);
      half8 pa1 = *(const half8*)(&Pl[wave][(16 + r16) * 40 + g * 8]);
#pragma unroll
      for (int n = 0; n < 8; ++n) {
        int d = n * 16 + r16;
        half8 vb = *(const half8*)(Vt + d * 32 + ((g ^ ((d >> 1) & 3)) << 3));
        O[0][n] = __builtin_amdgcn_mfma_f32_16x16x32_f16(pa0, vb, O[0][n], 0, 0, 0);
        O[1][n] = __builtin_amdgcn_mfma_f32_16x16x32_f16(pa1, vb, O[1][n], 0, 0, 0);
      }
    }
  }

  // --- epilogue: y[t][h*128+d] f16 ---
#pragma unroll
  for (int i = 0; i < 2; ++i)
#pragma unroll
    for (int ri = 0; ri < 4; ++ri) {
      float inv = 1.0f / lrow[i][ri];
      int t = q0 + i * 16 + g * 4 + ri;
      size_t rb = (size_t)t * 4096 + h * 128 + r16;
#pragma unroll
      for (int n = 0; n < 8; ++n) yf[rb + n * 16] = (_Float16)(O[i][n][ri] * inv);
    }
}

// ------------------------------------------------------------------
extern "C" void kernel_launch(void* const* d_in, const int* in_sizes, int n_in,
                              void* d_out, int out_size, void* d_ws, size_t ws_size,
                              hipStream_t stream) {
  const float* x = (const float*)d_in[0];
  const float* w_attn = (const float*)d_in[1];
  const float* b_attn = (const float*)d_in[2];
  const float* w_proj = (const float*)d_in[3];
  const float* b_proj = (const float*)d_in[4];
  float* out = (float*)d_out;

  // workspace carve (all f16): 218.1 MB total
  _Float16* xh = (_Float16*)d_ws;
  _Float16* wa = xh + (size_t)2048 * 4096;
  _Float16* wp = wa + (size_t)12288 * 4096;
  _Float16* qfp = wp + (size_t)4096 * 4096;
  _Float16* kfp = qfp + (size_t)32 * 2048 * 128;
  _Float16* vfp = kfp + (size_t)32 * 2048 * 128;
  _Float16* yf = vfp + (size_t)32 * 2048 * 128;

  cvt_f32_f16<<<(2048 * 4096 / 8 + 255) / 256, 256, 0, stream>>>(x, xh, 2048 * 4096 / 8);
  cvt_f32_f16<<<(12288 * 4096 / 8 + 255) / 256, 256, 0, stream>>>(w_attn, wa, 12288 * 4096 / 8);
  cvt_f32_f16<<<(4096 * 4096 / 8 + 255) / 256, 256, 0, stream>>>(w_proj, wp, 4096 * 4096 / 8);

  // qkv = x @ Wa^T + b, fused RoPE epilogue -> q/k/v [H][T][D] f16
  gemm_nt<<<dim3(96, 16), 256, 0, stream>>>(xh, wa, b_attn, nullptr, 2048, 12288, 4096, 1,
                                            qfp, kfp, vfp);
  attn<<<512, 256, 0, stream>>>(qfp, kfp, vfp, yf);
  // out = y @ Wp^T + b
  gemm_nt<<<dim3(32, 16), 256, 0, stream>>>(yf, wp, b_proj, out, 2048, 4096, 4096, 0,
                                            nullptr, nullptr, nullptr);
}